// Round 1
// baseline (188.326 us; speedup 1.0000x reference)
//
#include <hip/hip_runtime.h>

#define N_RAYS 65536
#define N_PTS 128
#define FEAT 3
#define FAR_DELTA 1e10f

// One 64-lane wave per ray; lane L owns samples 2L and 2L+1 (so depth/density
// load as float2 and feature as 3x float2, all coalesced). Exclusive prefix
// sum of per-pair tau via shift-then-inclusive wave scan (avoids cancellation
// against the 1e10 sentinel tau in lane 63). 4 waves / 256-thread block.
__global__ __launch_bounds__(256) void volrend_kernel(
    const float* __restrict__ depth,
    const float* __restrict__ density,
    const float* __restrict__ feature,
    float* __restrict__ out)
{
    const int wave = threadIdx.x >> 6;
    const int lane = threadIdx.x & 63;
    const int ray  = (blockIdx.x << 2) + wave;

    const int base = ray * N_PTS;          // ray-contiguous layout
    const float2 d   = *(const float2*)(depth   + base + 2 * lane);
    const float2 rho = *(const float2*)(density + base + 2 * lane);

    // delta for sample 2L is d.y - d.x; delta for 2L+1 needs next lane's d.x.
    float next_dx = __shfl_down(d.x, 1);
    float delta_a = d.y - d.x;
    float delta_b = (lane == 63) ? FAR_DELTA : (next_dx - d.y);

    float tau_a = rho.x * delta_a;
    float tau_b = rho.y * delta_b;     // lane 63: ~1e10 * density (sentinel)
    float pair  = tau_a + tau_b;

    // Exclusive wave scan: shift by 1 (lane0 -> 0), then inclusive scan.
    // The huge lane-63 tau never enters any lane's exclusive sum, so no
    // catastrophic cancellation.
    float e = __shfl_up(pair, 1);
    if (lane == 0) e = 0.0f;
    #pragma unroll
    for (int off = 1; off < 64; off <<= 1) {
        float t = __shfl_up(e, off);
        if (lane >= off) e += t;
    }
    // e = sum of pair-taus of lanes < L = cum tau before sample 2L

    float Ta   = __expf(-e);                          // T at sample 2L
    float Tmid = __expf(-(e + tau_a));                // T at sample 2L+1
    float Tend = __expf(-(e + tau_a + tau_b));        // T after pair (0 @63)
    float w_a = Ta - Tmid;       // = T * (1 - exp(-tau))
    float w_b = Tmid - Tend;

    const float2* f2 = (const float2*)(feature + (size_t)ray * (N_PTS * FEAT)
                                       + 6 * lane);
    float2 fa = f2[0];   // feat[2L].rgb = fa.x fa.y fb.x
    float2 fb = f2[1];   // feat[2L+1].rgb = fb.y fc.x fc.y
    float2 fc = f2[2];

    float acc0 = w_a * fa.x + w_b * fb.y;
    float acc1 = w_a * fa.y + w_b * fc.x;
    float acc2 = w_a * fb.x + w_b * fc.y;
    float acc3 = w_a * d.x  + w_b * d.y;   // depth_out

    #pragma unroll
    for (int off = 32; off > 0; off >>= 1) {
        acc0 += __shfl_down(acc0, off);
        acc1 += __shfl_down(acc1, off);
        acc2 += __shfl_down(acc2, off);
        acc3 += __shfl_down(acc3, off);
    }

    if (lane == 0) {
        *(float4*)(out + ray * 4) = make_float4(acc0, acc1, acc2, acc3);
    }
}

extern "C" void kernel_launch(void* const* d_in, const int* in_sizes, int n_in,
                              void* d_out, int out_size, void* d_ws, size_t ws_size,
                              hipStream_t stream) {
    const float* depth   = (const float*)d_in[0];
    const float* density = (const float*)d_in[1];
    const float* feature = (const float*)d_in[2];
    float* out = (float*)d_out;

    // 4 rays per 256-thread block (one wave per ray)
    dim3 grid(N_RAYS / 4);
    dim3 block(256);
    volrend_kernel<<<grid, block, 0, stream>>>(depth, density, feature, out);
}